// Round 1
// baseline (149.310 us; speedup 1.0000x reference)
//
#include <hip/hip_runtime.h>

#define C_IN   64
#define HW_DIM 64
#define C_OUT  128
#define FEAT   576      // C_IN * 9
#define NG     8
#define KSPL   4608     // FEAT * NG
#define KTOT   5184     // KSPL + FEAT
#define BM     64       // pixels per block = one image row
#define BK     64
#define NSPL_STEPS 72   // KSPL / BK
#define NSTEPS 81       // + FEAT/BK = 9 base steps
#define LDK    72       // BK + 8 pad (bf16 elems) -> 144B row stride, 2-way-free banks

typedef __attribute__((ext_vector_type(8))) __bf16 bf16x8;
typedef __attribute__((ext_vector_type(4))) float  f32x4;

// ---------------- weight prep: fuse spline_w[4608,128] + base_w[576,128]
// into transposed bf16 Wt[128][5184] in d_ws (coalesced LDS transpose) ----
__global__ __launch_bounds__(256)
void prep_wt(const float* __restrict__ sw, const float* __restrict__ bw,
             __bf16* __restrict__ wt)
{
  __shared__ float T[64][65];           // +1 pad: conflict-free both phases
  const int id = blockIdx.x;
  const int ct = id & 1;                // 2 col tiles of 64
  const int kt = id >> 1;               // 81 k tiles of 64
  const int c0 = ct * 64;
  const int k0 = kt * 64;
  const int t  = threadIdx.x;
  {
    const int cc = t & 63;              // lanes -> consecutive cols: coalesced
    const int kq = (t >> 6) * 16;
#pragma unroll
    for (int i = 0; i < 16; ++i) {
      const int kk = kq + i;
      const int k  = k0 + kk;
      float v;
      if (k < KSPL) v = sw[(size_t)k * C_OUT + c0 + cc];
      else          v = bw[(size_t)(k - KSPL) * C_OUT + c0 + cc];
      T[cc][kk] = v;
    }
  }
  __syncthreads();
  {
    const int kk = t & 63;              // lanes -> consecutive k: coalesced write
    const int cq = (t >> 6) * 16;
#pragma unroll
    for (int i = 0; i < 16; ++i) {
      const int cc = cq + i;
      wt[(size_t)(c0 + cc) * KTOT + k0 + kk] = (__bf16)T[cc][kk];
    }
  }
}

// ---------------- fused im2col + RBF expansion + GEMM ----------------
// D[co][pix] = sum_k Wt[co][k] * A[pix][k],  A = [basis(p) | silu(p)]
// 512 blocks (1 image row each), 4 waves of 32(pix) x 64(co).
__global__ __launch_bounds__(256, 2)
void kan_gemm(const float* __restrict__ x, const float* __restrict__ grid,
              const __bf16* __restrict__ wt, const float* __restrict__ base_b,
              float* __restrict__ out)
{
  __shared__ __align__(16) __bf16 As[BM][LDK];     // basis tile [pix][k]
  __shared__ __align__(16) __bf16 Bs[C_OUT][LDK];  // weight tile [co][k]

  const int t  = threadIdx.x;
  const int m0 = blockIdx.x * BM;       // first pixel
  const int b  = m0 >> 12;              // image (4096 px each)
  const int y0 = (m0 & 4095) >> 6;      // image row

  // RBF: exp(-((p-g)/h)^2) = exp2(-(p*A - g*A)^2), A = (7/4)*sqrt(log2 e)
  const float ALPHA = 1.75f * 1.2011224087864498f;
  float beta[NG];
#pragma unroll
  for (int g = 0; g < NG; ++g) beta[g] = grid[g] * ALPHA;

  const int lane = t & 63;
  const int wid  = t >> 6;
  const int wr   = wid >> 1;            // pixel half (32)
  const int wc   = wid & 1;             // channel half (64)
  const int l15  = lane & 15;
  const int g4   = lane >> 4;

  f32x4 acc[4][2];                      // [n over 64 co][m over 32 px]
#pragma unroll
  for (int n = 0; n < 4; ++n)
#pragma unroll
    for (int m = 0; m < 2; ++m)
      acc[n][m] = f32x4{0.f, 0.f, 0.f, 0.f};

  const int sr = t & 63;                // staging pixel x-coord (coalesced lanes)
  const int sq = t >> 6;                // 0..3
  const float* xb = x + (size_t)b * (C_IN * HW_DIM * HW_DIM);

  const int bc  = t >> 1;               // B-staging: col 0..127
  const int bkh = (t & 1) * 32;         // k half
  const __bf16* wsrc = wt + (size_t)bc * KTOT + bkh;

  for (int step = 0; step < NSTEPS; ++step) {
    __syncthreads();                    // previous compute done with LDS
    // ---- stage B: 64 k x 128 co, bf16, 4x16B per thread
    {
      const __bf16* s = wsrc + step * BK;
#pragma unroll
      for (int j = 0; j < 4; ++j)
        *(bf16x8*)(&Bs[bc][bkh + j * 8]) = *(const bf16x8*)(s + j * 8);
    }
    // ---- stage A
    if (step < NSPL_STEPS) {            // spline phase: 8 feats x 8 grids
      const int f0 = step * 8;
#pragma unroll
      for (int i = 0; i < 2; ++i) {
        const int lf = sq + 4 * i;
        const int f  = f0 + lf;
        const int c  = f / 9;
        const int j  = f - 9 * c;
        const int kh = j / 3;
        const int kw = j - 3 * kh;
        const int yy = y0 + kh - 1;
        const int xx = sr + kw - 1;
        float p = 0.f;
        if ((unsigned)yy < HW_DIM && (unsigned)xx < HW_DIM)
          p = xb[(c * HW_DIM + yy) * HW_DIM + xx];
        const float pa = p * ALPHA;
        bf16x8 pk;
#pragma unroll
        for (int g = 0; g < NG; ++g) {
          const float z = pa - beta[g];
          pk[g] = (__bf16)__expf(-z * z * 0.6931471805599453f); // == exp2(-z^2)
        }
        *(bf16x8*)(&As[sr][lf * 8]) = pk;
      }
    } else {                            // base phase: 64 feats of silu(p)
      const int f0 = (step - NSPL_STEPS) * 64;
#pragma unroll
      for (int i = 0; i < 2; ++i) {
        const int lf8 = (sq + 4 * i) * 8;
        bf16x8 pk;
#pragma unroll
        for (int jj = 0; jj < 8; ++jj) {
          const int f  = f0 + lf8 + jj;
          const int c  = f / 9;
          const int j  = f - 9 * c;
          const int kh = j / 3;
          const int kw = j - 3 * kh;
          const int yy = y0 + kh - 1;
          const int xx = sr + kw - 1;
          float p = 0.f;
          if ((unsigned)yy < HW_DIM && (unsigned)xx < HW_DIM)
            p = xb[(c * HW_DIM + yy) * HW_DIM + xx];
          const float e = __expf(-p);
          pk[jj] = (__bf16)(p * __builtin_amdgcn_rcpf(1.f + e));
        }
        *(bf16x8*)(&As[sr][lf8]) = pk;
      }
    }
    __syncthreads();
    // ---- compute: 16 MFMA / step (weights as A-operand -> C^T, coalesced stores)
#pragma unroll
    for (int ks = 0; ks < 2; ++ks) {
      const int kk = ks * 32 + g4 * 8;
      bf16x8 wf[4], xf[2];
#pragma unroll
      for (int n = 0; n < 4; ++n)
        wf[n] = *(const bf16x8*)(&Bs[wc * 64 + n * 16 + l15][kk]);
#pragma unroll
      for (int m = 0; m < 2; ++m)
        xf[m] = *(const bf16x8*)(&As[wr * 32 + m * 16 + l15][kk]);
#pragma unroll
      for (int n = 0; n < 4; ++n)
#pragma unroll
        for (int m = 0; m < 2; ++m)
          acc[n][m] = __builtin_amdgcn_mfma_f32_16x16x32_bf16(
              wf[n], xf[m], acc[n][m], 0, 0, 0);
    }
  }

  // ---- epilogue: D[co][pix], col(lane&15)=pix -> consecutive lanes = consecutive x
  const int prow = m0 & 4095;           // y0*64
#pragma unroll
  for (int n = 0; n < 4; ++n) {
    const int co = wc * 64 + n * 16 + g4 * 4;
#pragma unroll
    for (int m = 0; m < 2; ++m) {
      const int pl = wr * 32 + m * 16 + l15;
      float* o = out + (size_t)(b * C_OUT + co) * 4096 + prow + pl;
#pragma unroll
      for (int i = 0; i < 4; ++i)
        o[(size_t)i * 4096] = acc[n][m][i] + base_b[co + i];
    }
  }
}

extern "C" void kernel_launch(void* const* d_in, const int* in_sizes, int n_in,
                              void* d_out, int out_size, void* d_ws, size_t ws_size,
                              hipStream_t stream) {
  const float* x    = (const float*)d_in[0];
  const float* grid = (const float*)d_in[1];
  const float* sw   = (const float*)d_in[2];
  const float* bw   = (const float*)d_in[3];
  const float* bb   = (const float*)d_in[4];
  float* out = (float*)d_out;
  __bf16* wt = (__bf16*)d_ws;           // 128*5184*2B = 1.33 MB scratch

  prep_wt<<<162, 256, 0, stream>>>(sw, bw, wt);
  kan_gemm<<<512, 256, 0, stream>>>(x, grid, wt, bb, out);
}

// Round 3
// 112.869 us; speedup vs baseline: 1.3229x; 1.3229x over previous
//
#include <hip/hip_runtime.h>

#define C_IN   64
#define HW_DIM 64
#define C_OUT  128
#define FEAT   576      // C_IN * 9
#define NG     8
#define KSPL   4608     // FEAT * NG
#define KTOT   5184     // KSPL + FEAT
#define BM     32       // pixels per block (half an image row)
#define BK     64
#define NSPL_STEPS 72   // KSPL / BK
#define NSTEPS 81       // + FEAT/BK = 9 base steps

typedef __attribute__((ext_vector_type(8))) __bf16 bf16x8;
typedef __attribute__((ext_vector_type(4))) float  f32x4;

// ---------------------------------------------------------------------------
// Weight prep: fuse spline_w[4608,128] + base_w[576,128] into d_ws as
// wt2[81 steps][128 co][64 k] bf16, with the 16B k-granule XOR-swizzled by
// (co&7) so a LINEAR global_load_lds fill yields the swizzled LDS layout
// (guide G21: pre-swizzled source + swizzled read).
// ---------------------------------------------------------------------------
__global__ __launch_bounds__(256)
void prep_wt(const float* __restrict__ sw, const float* __restrict__ bw,
             __bf16* __restrict__ wt2)
{
  const int step = blockIdx.x;          // 0..80
  const int t    = threadIdx.x;
  const int co   = t & 127;             // lanes -> consecutive co: coalesced reads
  const int half = t >> 7;              // 0..1
#pragma unroll
  for (int q = 0; q < 4; ++q) {
    const int g = half * 4 + q;         // k-granule 0..7 (8 bf16 = 16B)
    bf16x8 pk;
#pragma unroll
    for (int e = 0; e < 8; ++e) {
      const int k = step * BK + g * 8 + e;
      float v;
      if (k < KSPL) v = sw[(size_t)k * C_OUT + co];
      else          v = bw[(size_t)(k - KSPL) * C_OUT + co];
      pk[e] = (__bf16)v;
    }
    const int gs = g ^ (co & 7);        // XOR swizzle on 16B granule
    *(bf16x8*)(wt2 + (size_t)step * (C_OUT * BK) + co * BK + gs * 8) = pk;
  }
}

static __device__ __forceinline__ void gload16(const __bf16* g, __bf16* l) {
  __builtin_amdgcn_global_load_lds(
      (const __attribute__((address_space(1))) void*)g,
      (__attribute__((address_space(3))) void*)l, 16, 0, 0);
}

// ---------------------------------------------------------------------------
// Fused im2col + RBF basis + GEMM.  D[co][pix] = sum_k Wt[co][k]*A[pix][k]
// 1024 blocks x 256 thr (4 waves, each 32px x 32co), 2-phase pipeline:
//   stage B(step+1) via global_load_lds  ||  compute A(step+1) -> LDS
//   MFMA(step); one barrier per step.
// LDS 40KB -> 4 blocks/CU = 16 waves/CU.
// ---------------------------------------------------------------------------
__global__ __launch_bounds__(256, 4)
void kan_gemm(const float* __restrict__ x, const float* __restrict__ grid,
              const __bf16* __restrict__ wt2, const float* __restrict__ base_b,
              float* __restrict__ out)
{
  __shared__ __align__(16) __bf16 As[2][BM][BK];      // 2 x 4 KB
  __shared__ __align__(16) __bf16 Bs[2][C_OUT][BK];   // 2 x 16 KB

  const int t    = threadIdx.x;
  const int lane = t & 63;
  const int wid  = t >> 6;
  const int l15  = lane & 15;
  const int g4   = lane >> 4;
  const int co0  = wid * 32;            // wave's output-channel range

  const int m0  = blockIdx.x * BM;      // first pixel (global)
  const int b   = m0 >> 12;             // image
  const int rem = m0 & 4095;
  const int y0  = rem >> 6;             // image row
  const int x0  = rem & 63;             // 0 or 32

  const float* xb = x + (size_t)b * (C_IN * HW_DIM * HW_DIM);

  // RBF: exp(-((p-g)/h)^2), h = 4/7  ->  __expf(-(1.75*(p-g))^2)
  const float ALPHA = 1.75f;
  float gb[NG];
#pragma unroll
  for (int g = 0; g < NG; ++g) gb[g] = grid[g] * ALPHA;

  // A-staging role: thread owns (pixel px, k-granule gran)
  const int px   = t & 31;
  const int gran = t >> 5;              // 0..7

  f32x4 acc[2][2];                      // [n over 32 co][m over 32 px]
#pragma unroll
  for (int n = 0; n < 2; ++n)
#pragma unroll
    for (int m = 0; m < 2; ++m)
      acc[n][m] = f32x4{0.f, 0.f, 0.f, 0.f};

  // ---- A-tile compute into As[buf] for k-step `step` ----
  auto computeA = [&](int buf, int step) {
    bf16x8 pk;
    if (step < NSPL_STEPS) {            // spline: 1 feature x 8 grid values
      const int f  = step * 8 + gran;
      const int c  = f / 9;
      const int j  = f - 9 * c;
      const int kh = j / 3;
      const int kw = j - 3 * kh;
      const int yy = y0 + kh - 1;
      const int xx = x0 + px + kw - 1;
      float p = 0.f;
      if ((unsigned)yy < HW_DIM && (unsigned)xx < HW_DIM)
        p = xb[(c * HW_DIM + yy) * HW_DIM + xx];
      const float pa = p * ALPHA;
#pragma unroll
      for (int g = 0; g < NG; ++g) {
        const float z = pa - gb[g];
        pk[g] = (__bf16)__expf(-z * z);
      }
    } else {                            // base: 8 features of silu(p)
      const int f0 = (step - NSPL_STEPS) * BK + gran * 8;
#pragma unroll
      for (int jj = 0; jj < 8; ++jj) {
        const int f  = f0 + jj;
        const int c  = f / 9;
        const int j  = f - 9 * c;
        const int kh = j / 3;
        const int kw = j - 3 * kh;
        const int yy = y0 + kh - 1;
        const int xx = x0 + px + kw - 1;
        float p = 0.f;
        if ((unsigned)yy < HW_DIM && (unsigned)xx < HW_DIM)
          p = xb[(c * HW_DIM + yy) * HW_DIM + xx];
        const float e = __expf(-p);
        pk[jj] = (__bf16)(p * __builtin_amdgcn_rcpf(1.f + e));
      }
    }
    const int gs = gran ^ (px & 7);     // same XOR family as B side
    *(bf16x8*)(&As[buf][px][gs * 8]) = pk;
  };

  // ---- B-tile stage via async global->LDS (linear fill of pre-swizzled src) ----
  auto stageB = [&](int buf, int step) {
    const __bf16* src = wt2 + (size_t)step * (C_OUT * BK) + wid * 2048 + lane * 8;
    __bf16* dst = &Bs[buf][0][0] + wid * 2048;
#pragma unroll
    for (int j = 0; j < 4; ++j)
      gload16(src + j * 512, dst + j * 512);
  };

  // prologue: fill buffer 0
  stageB(0, 0);
  computeA(0, 0);
  __syncthreads();

  int cur = 0;
  for (int step = 0; step < NSTEPS; ++step) {
    const int nxt = cur ^ 1;
    if (step + 1 < NSTEPS) {
      stageB(nxt, step + 1);            // async, drains at the barrier below
      computeA(nxt, step + 1);          // x-loads + VALU overlap B-load latency
    }
    // ---- MFMA on current buffers (swizzled b128 reads: 2-way = free) ----
#pragma unroll
    for (int ks = 0; ks < 2; ++ks) {
      bf16x8 wf[2], xf[2];
#pragma unroll
      for (int n = 0; n < 2; ++n) {
        const int r = co0 + n * 16 + l15;
        wf[n] = *(const bf16x8*)(&Bs[cur][r][(((ks * 4 + g4) ^ (r & 7)) * 8)]);
      }
#pragma unroll
      for (int m = 0; m < 2; ++m) {
        const int pr = m * 16 + l15;
        xf[m] = *(const bf16x8*)(&As[cur][pr][(((ks * 4 + g4) ^ (pr & 7)) * 8)]);
      }
#pragma unroll
      for (int n = 0; n < 2; ++n)
#pragma unroll
        for (int m = 0; m < 2; ++m)
          acc[n][m] = __builtin_amdgcn_mfma_f32_16x16x32_bf16(
              wf[n], xf[m], acc[n][m], 0, 0, 0);
    }
    __syncthreads();                    // drains vmcnt (B loads) + lgkm (A writes)
    cur = nxt;
  }

  // ---- epilogue: D[co][pix]; lanes (l15) -> consecutive x: coalesced ----
#pragma unroll
  for (int n = 0; n < 2; ++n) {
    const int co = co0 + n * 16 + g4 * 4;
#pragma unroll
    for (int m = 0; m < 2; ++m) {
      const int pl = m * 16 + l15;
      float* o = out + (size_t)(b * C_OUT + co) * 4096 + y0 * 64 + x0 + pl;
#pragma unroll
      for (int i = 0; i < 4; ++i)
        o[(size_t)i * 4096] = acc[n][m][i] + base_b[co + i];
    }
  }
}

extern "C" void kernel_launch(void* const* d_in, const int* in_sizes, int n_in,
                              void* d_out, int out_size, void* d_ws, size_t ws_size,
                              hipStream_t stream) {
  const float* x    = (const float*)d_in[0];
  const float* grid = (const float*)d_in[1];
  const float* sw   = (const float*)d_in[2];
  const float* bw   = (const float*)d_in[3];
  const float* bb   = (const float*)d_in[4];
  float* out = (float*)d_out;
  __bf16* wt2 = (__bf16*)d_ws;          // 81*128*64*2B = 1.33 MB scratch

  prep_wt<<<NSTEPS, 256, 0, stream>>>(sw, bw, wt2);
  kan_gemm<<<1024, 256, 0, stream>>>(x, grid, wt2, bb, out);
}

// Round 4
// 111.187 us; speedup vs baseline: 1.3429x; 1.0151x over previous
//
#include <hip/hip_runtime.h>

#define C_IN   64
#define HW_DIM 64
#define C_OUT  128
#define NG     8
#define KSPL   4608     // 576 * 8
#define BM     64       // pixels per block = one image row
#define BK     64
#define NSPL_STEPS 72   // KSPL / BK
#define NSTEPS 81
#define NPAD   66       // padded H/W
#define NEXP   (8 * C_IN * NPAD * NPAD)   // 2,230,272 padded elements

// d_ws layout (bytes)
#define WT_BYTES 1327104                  // 81*128*64*2
#define XE_OFF   WT_BYTES
#define XE_BYTES (NEXP * NG * 2)          // 35,684,352
#define SE_OFF   (XE_OFF + XE_BYTES)

typedef __attribute__((ext_vector_type(8))) __bf16 bf16x8;
typedef __attribute__((ext_vector_type(4))) float  f32x4;

// --------------------------------------------------------------------------
// Weight prep: spline_w[4608,128] ++ base_w[576,128] -> wt2[81][128 co][64 k]
// bf16, 16B k-granule XOR-swizzled by (co&7) so linear global_load_lds fill
// yields the swizzled LDS layout (G21).
// --------------------------------------------------------------------------
__global__ __launch_bounds__(256)
void prep_wt(const float* __restrict__ sw, const float* __restrict__ bw,
             __bf16* __restrict__ wt2)
{
  const int step = blockIdx.x;
  const int t    = threadIdx.x;
  const int co   = t & 127;
  const int half = t >> 7;
#pragma unroll
  for (int q = 0; q < 4; ++q) {
    const int g = half * 4 + q;
    bf16x8 pk;
#pragma unroll
    for (int e = 0; e < 8; ++e) {
      const int k = step * BK + g * 8 + e;
      float v;
      if (k < KSPL) v = sw[(size_t)k * C_OUT + co];
      else          v = bw[(size_t)(k - KSPL) * C_OUT + co];
      pk[e] = (__bf16)v;
    }
    const int gs = g ^ (co & 7);
    *(bf16x8*)(wt2 + (size_t)step * (C_OUT * BK) + co * BK + gs * 8) = pk;
  }
}

// --------------------------------------------------------------------------
// Basis/silu expansion: XE[bc][yp][xp][8] = exp(-(1.75(p-g))^2), SE = silu(p).
// p = 0 outside the image (halo rows/cols) -> halo holds basis(0), silu(0).
// One thread per padded element; all loads/stores coalesced.
// --------------------------------------------------------------------------
__global__ __launch_bounds__(256)
void expand(const float* __restrict__ x, const float* __restrict__ grid,
            __bf16* __restrict__ xe, __bf16* __restrict__ se)
{
  const int idx = blockIdx.x * 256 + threadIdx.x;
  if (idx >= NEXP) return;
  const int xp = idx % NPAD;
  const int r  = idx / NPAD;
  const int yp = r % NPAD;
  const int bc = r / NPAD;

  float p = 0.f;
  if (xp >= 1 && xp <= HW_DIM && yp >= 1 && yp <= HW_DIM)
    p = x[(size_t)bc * (HW_DIM * HW_DIM) + (yp - 1) * HW_DIM + (xp - 1)];

  bf16x8 v;
#pragma unroll
  for (int g = 0; g < NG; ++g) {
    const float z = 1.75f * (p - grid[g]);
    v[g] = (__bf16)__expf(-z * z);
  }
  *(bf16x8*)(xe + (size_t)idx * NG) = v;
  const float e = __expf(-p);
  se[idx] = (__bf16)(p * __builtin_amdgcn_rcpf(1.f + e));
}

static __device__ __forceinline__ void gload16(const __bf16* g, __bf16* l) {
  __builtin_amdgcn_global_load_lds(
      (const __attribute__((address_space(1))) void*)g,
      (__attribute__((address_space(3))) void*)l, 16, 0, 0);
}

// --------------------------------------------------------------------------
// GEMM: D[co][pix] = sum_k Wt[co][k] * A[pix][k], A = [basis | silu] gathered
// from precomputed XE/SE. 512 blocks (1 image row), 4 waves of 64px x 32co,
// 2-phase pipeline, 16 MFMA/step/wave.
// --------------------------------------------------------------------------
__global__ __launch_bounds__(256, 2)
void kan_gemm(const __bf16* __restrict__ xe, const __bf16* __restrict__ se,
              const __bf16* __restrict__ wt2, const float* __restrict__ base_b,
              float* __restrict__ out)
{
  __shared__ __align__(16) __bf16 As[2][BM][BK];      // 2 x 8 KB
  __shared__ __align__(16) __bf16 Bs[2][C_OUT][BK];   // 2 x 16 KB

  const int t    = threadIdx.x;
  const int lane = t & 63;
  const int wid  = t >> 6;
  const int l15  = lane & 15;
  const int g4   = lane >> 4;
  const int co0  = wid * 32;

  // bijective XCD swizzle: 512 blocks = 8 XCDs x 64 chunks
  const int bid = blockIdx.x;
  const int swz = (bid & 7) * 64 + (bid >> 3);
  const int b   = swz >> 6;             // image
  const int y0  = swz & 63;             // image row

  const int px = t & 63;                // staging pixel (lane-coalesced)
  const int q  = t >> 6;                // granule quarter 0..3

  f32x4 acc[2][4];
#pragma unroll
  for (int n = 0; n < 2; ++n)
#pragma unroll
    for (int m = 0; m < 4; ++m)
      acc[n][m] = f32x4{0.f, 0.f, 0.f, 0.f};

  // ---- A-tile stage: gather 16B basis granules (or silu scalars) ----
  auto stageA = [&](int buf, int step) {
    if (step < NSPL_STEPS) {
#pragma unroll
      for (int h = 0; h < 2; ++h) {
        const int gran = q + h * 4;
        const int f  = step * 8 + gran;
        const int c  = f / 9;
        const int j  = f - 9 * c;
        const int kh = j / 3;
        const int kw = j - 3 * kh;
        const size_t src = ((size_t)((b * C_IN + c) * NPAD + y0 + kh) * NPAD
                            + px + kw) * NG;
        const bf16x8 v = *(const bf16x8*)(xe + src);
        *(bf16x8*)(&As[buf][px][(gran ^ (px & 7)) * 8]) = v;
      }
    } else {
      const int f0 = (step - NSPL_STEPS) * BK;
#pragma unroll
      for (int h = 0; h < 2; ++h) {
        const int gran = q + h * 4;
        bf16x8 v;
#pragma unroll
        for (int jj = 0; jj < 8; ++jj) {
          const int f  = f0 + gran * 8 + jj;
          const int c  = f / 9;
          const int j  = f - 9 * c;
          const int kh = j / 3;
          const int kw = j - 3 * kh;
          v[jj] = se[(size_t)((b * C_IN + c) * NPAD + y0 + kh) * NPAD + px + kw];
        }
        *(bf16x8*)(&As[buf][px][(gran ^ (px & 7)) * 8]) = v;
      }
    }
  };

  // ---- B-tile stage via async global->LDS (linear fill of pre-swz src) ----
  auto stageB = [&](int buf, int step) {
    const __bf16* src = wt2 + (size_t)step * (C_OUT * BK) + wid * 2048 + lane * 8;
    __bf16* dst = &Bs[buf][0][0] + wid * 2048;
#pragma unroll
    for (int j = 0; j < 4; ++j)
      gload16(src + j * 512, dst + j * 512);
  };

  stageB(0, 0);
  stageA(0, 0);
  __syncthreads();

  int cur = 0;
  for (int step = 0; step < NSTEPS; ++step) {
    const int nxt = cur ^ 1;
    if (step + 1 < NSTEPS) {
      stageB(nxt, step + 1);            // async, drains at barrier
      stageA(nxt, step + 1);            // coalesced XE/SE loads hide B latency
    }
#pragma unroll
    for (int ks = 0; ks < 2; ++ks) {
      bf16x8 wf[2], xf[4];
#pragma unroll
      for (int n = 0; n < 2; ++n) {
        const int r = co0 + n * 16 + l15;
        wf[n] = *(const bf16x8*)(&Bs[cur][r][(((ks * 4 + g4) ^ (r & 7)) * 8)]);
      }
#pragma unroll
      for (int m = 0; m < 4; ++m) {
        const int pr = m * 16 + l15;
        xf[m] = *(const bf16x8*)(&As[cur][pr][(((ks * 4 + g4) ^ (pr & 7)) * 8)]);
      }
#pragma unroll
      for (int n = 0; n < 2; ++n)
#pragma unroll
        for (int m = 0; m < 4; ++m)
          acc[n][m] = __builtin_amdgcn_mfma_f32_16x16x32_bf16(
              wf[n], xf[m], acc[n][m], 0, 0, 0);
    }
    __syncthreads();
    cur = nxt;
  }

  // ---- epilogue: D[co][pix]; l15 -> consecutive x: coalesced ----
#pragma unroll
  for (int n = 0; n < 2; ++n) {
    const int co = co0 + n * 16 + g4 * 4;
#pragma unroll
    for (int m = 0; m < 4; ++m) {
      const int pl = m * 16 + l15;
      float* o = out + (size_t)(b * C_OUT + co) * 4096 + y0 * 64 + pl;
#pragma unroll
      for (int i = 0; i < 4; ++i)
        o[(size_t)i * 4096] = acc[n][m][i] + base_b[co + i];
    }
  }
}

extern "C" void kernel_launch(void* const* d_in, const int* in_sizes, int n_in,
                              void* d_out, int out_size, void* d_ws, size_t ws_size,
                              hipStream_t stream) {
  const float* x    = (const float*)d_in[0];
  const float* grid = (const float*)d_in[1];
  const float* sw   = (const float*)d_in[2];
  const float* bw   = (const float*)d_in[3];
  const float* bb   = (const float*)d_in[4];
  float* out = (float*)d_out;

  __bf16* wt2 = (__bf16*)d_ws;
  __bf16* xe  = (__bf16*)((char*)d_ws + XE_OFF);
  __bf16* se  = (__bf16*)((char*)d_ws + SE_OFF);

  prep_wt<<<NSTEPS, 256, 0, stream>>>(sw, bw, wt2);
  expand<<<(NEXP + 255) / 256, 256, 0, stream>>>(x, grid, xe, se);
  kan_gemm<<<512, 256, 0, stream>>>(xe, se, wt2, bb, out);
}

// Round 5
// 92.971 us; speedup vs baseline: 1.6060x; 1.1959x over previous
//
#include <hip/hip_runtime.h>

#define C_IN   64
#define HW_DIM 64
#define C_OUT  128
#define NG     8
#define KSPL   4608     // 576 * 8
#define BM     64       // pixels per block = one image row
#define BK     64
#define NSPL_STEPS 72   // KSPL / BK
#define NSTEPS 81
#define NPAD   66
#define NEXP   (8 * C_IN * NPAD * NPAD)   // 2,230,272 padded elements

// d_ws layout (bytes)
#define WT_BYTES 1327104                  // 81*128*64*2
#define XE_OFF   WT_BYTES
#define XE_BYTES (NEXP * NG * 2)          // 35,684,352
#define SE_OFF   (XE_OFF + XE_BYTES)

typedef __attribute__((ext_vector_type(8))) __bf16 bf16x8;
typedef __attribute__((ext_vector_type(4))) float  f32x4;

// --------------------------------------------------------------------------
// Weight prep: pack spline_w ++ base_w into per-wave MFMA-fragment order:
// wt3[step][wc][n][ks][lane][8]  (lane = g4*16+l15), value = W[co][k] with
// co = wc*32+n*16+l15, k = step*64+ks*32+g4*8+e.  A wave's 4 frag loads per
// step are 4 consecutive 1KB segments -> perfectly coalesced, no LDS needed.
// --------------------------------------------------------------------------
__global__ __launch_bounds__(256)
void prep_wt(const float* __restrict__ sw, const float* __restrict__ bw,
             __bf16* __restrict__ wt3)
{
  const int step = blockIdx.x;
  const int t    = threadIdx.x;
  const int wc   = t >> 6;
  const int lane = t & 63;
  const int l15  = lane & 15;
  const int g4   = lane >> 4;
#pragma unroll
  for (int n = 0; n < 2; ++n)
#pragma unroll
    for (int ks = 0; ks < 2; ++ks) {
      const int co = wc * 32 + n * 16 + l15;
      bf16x8 v;
#pragma unroll
      for (int e = 0; e < 8; ++e) {
        const int k = step * 64 + ks * 32 + g4 * 8 + e;
        float f;
        if (k < KSPL) f = sw[(size_t)k * C_OUT + co];
        else          f = bw[(size_t)(k - KSPL) * C_OUT + co];
        v[e] = (__bf16)f;
      }
      *(bf16x8*)(wt3 + (size_t)step * 8192 + wc * 2048 + (n * 2 + ks) * 512
                 + lane * 8) = v;
    }
}

// --------------------------------------------------------------------------
// Basis/silu expansion (unchanged): XE[bc][yp][xp][8], SE[bc][yp][xp].
// --------------------------------------------------------------------------
__global__ __launch_bounds__(256)
void expand(const float* __restrict__ x, const float* __restrict__ grid,
            __bf16* __restrict__ xe, __bf16* __restrict__ se)
{
  const int idx = blockIdx.x * 256 + threadIdx.x;
  if (idx >= NEXP) return;
  const int xp = idx % NPAD;
  const int r  = idx / NPAD;
  const int yp = r % NPAD;
  const int bc = r / NPAD;

  float p = 0.f;
  if (xp >= 1 && xp <= HW_DIM && yp >= 1 && yp <= HW_DIM)
    p = x[(size_t)bc * (HW_DIM * HW_DIM) + (yp - 1) * HW_DIM + (xp - 1)];

  bf16x8 v;
#pragma unroll
  for (int g = 0; g < NG; ++g) {
    const float z = 1.75f * (p - grid[g]);
    v[g] = (__bf16)__expf(-z * z);
  }
  *(bf16x8*)(xe + (size_t)idx * NG) = v;
  const float e = __expf(-p);
  se[idx] = (__bf16)(p * __builtin_amdgcn_rcpf(1.f + e));
}

// --------------------------------------------------------------------------
// GEMM: 512 blocks (1 image row), 4 waves of 64px x 32co.
// Spline phase (72 steps): A-frags direct XE->reg (granule == fragment),
// B-frags direct wt3->reg (wave-exclusive rows) -> ZERO barriers, 1-step
// software pipeline via unroll-by-2 with named register sets.
// Base phase (9 steps): silu gathers via double-buffered LDS As + barrier.
// --------------------------------------------------------------------------
__global__ __launch_bounds__(256, 2)
void kan_gemm(const __bf16* __restrict__ xe, const __bf16* __restrict__ se,
              const __bf16* __restrict__ wt3, const float* __restrict__ base_b,
              float* __restrict__ out)
{
  __shared__ __align__(16) __bf16 As[2][BM][BK];   // base phase only, 16 KB
  __shared__ int tbl[576];                         // c*4356 + kh*66 + kw

  const int t    = threadIdx.x;
  const int lane = t & 63;
  const int wid  = t >> 6;
  const int l15  = lane & 15;
  const int g4   = lane >> 4;

  // bijective XCD swizzle: 512 blocks = 8 XCDs x 64 -> one image per XCD
  const int bid = blockIdx.x;
  const int swz = (bid & 7) * 64 + (bid >> 3);
  const int b   = swz >> 6;             // image
  const int y0  = swz & 63;             // image row

  // feature -> padded-offset table (kills per-step /9 /3 address VALU)
  for (int f = t; f < 576; f += 256) {
    const int c  = f / 9;
    const int j  = f - 9 * c;
    const int kh = j / 3;
    const int kw = j - 3 * kh;
    tbl[f] = c * 4356 + kh * 66 + kw;
  }

  const int F0  = b * 278784 + y0 * 66 + l15;       // A-frag pixel base (l15)
  const int F0s = b * 278784 + y0 * 66 + (t & 63);  // base-stage pixel base

  f32x4 acc[2][4];
#pragma unroll
  for (int n = 0; n < 2; ++n)
#pragma unroll
    for (int m = 0; m < 4; ++m)
      acc[n][m] = f32x4{0.f, 0.f, 0.f, 0.f};

  auto loadB = [&](bf16x8 wf[2][2], int step) {
    const __bf16* wb = wt3 + (size_t)step * 8192 + wid * 2048 + lane * 8;
#pragma unroll
    for (int n = 0; n < 2; ++n)
#pragma unroll
      for (int ks = 0; ks < 2; ++ks)
        wf[n][ks] = *(const bf16x8*)(wb + (n * 2 + ks) * 512);
  };

  auto loadA = [&](bf16x8 xf[4][2], int step) {
#pragma unroll
    for (int ks = 0; ks < 2; ++ks) {
      const int f = step * 8 + ks * 4 + g4;
      const __bf16* ab = xe + ((size_t)(F0 + tbl[f])) * 8;
#pragma unroll
      for (int m = 0; m < 4; ++m)                   // px = m*16+l15: +256B imm
        xf[m][ks] = *(const bf16x8*)(ab + m * 128);
    }
  };

  auto mfmaS = [&](bf16x8 xf[4][2], bf16x8 wf[2][2]) {
#pragma unroll
    for (int ks = 0; ks < 2; ++ks)
#pragma unroll
      for (int n = 0; n < 2; ++n)
#pragma unroll
        for (int m = 0; m < 4; ++m)
          acc[n][m] = __builtin_amdgcn_mfma_f32_16x16x32_bf16(
              wf[n][ks], xf[m][ks], acc[n][m], 0, 0, 0);
  };

  __syncthreads();                      // tbl ready

  // ---- spline phase: barrier-free, 1-step-ahead pipeline ----
  bf16x8 xfA[4][2], xfB[4][2], wfA[2][2], wfB[2][2];
  loadA(xfA, 0); loadB(wfA, 0);
  for (int s = 0; s < NSPL_STEPS - 2; s += 2) {
    loadA(xfB, s + 1); loadB(wfB, s + 1);
    mfmaS(xfA, wfA);
    loadA(xfA, s + 2); loadB(wfA, s + 2);
    mfmaS(xfB, wfB);
  }
  loadA(xfB, NSPL_STEPS - 1); loadB(wfB, NSPL_STEPS - 1);
  mfmaS(xfA, wfA);                      // step 70 (in A-set)
  mfmaS(xfB, wfB);                      // step 71

  // ---- base phase: silu(p) patches via LDS (9 steps) ----
  auto stageA = [&](int buf, int bs) {
    const int q  = t >> 6;
    const int px = t & 63;
#pragma unroll
    for (int h = 0; h < 2; ++h) {
      const int gran = q + h * 4;
      bf16x8 v;
#pragma unroll
      for (int jj = 0; jj < 8; ++jj) {
        const int f = (bs - NSPL_STEPS) * 64 + gran * 8 + jj;
        v[jj] = se[(size_t)(F0s + tbl[f])];
      }
      *(bf16x8*)(&As[buf][px][(gran ^ (px & 7)) * 8]) = v;
    }
  };

  stageA(0, NSPL_STEPS);
  __syncthreads();
  for (int bs = NSPL_STEPS; bs < NSTEPS; ++bs) {
    const int cb = (bs - NSPL_STEPS) & 1;
    if (bs + 1 < NSTEPS) stageA(cb ^ 1, bs + 1);
    loadB(wfA, bs);
    bf16x8 xf[4][2];
#pragma unroll
    for (int ks = 0; ks < 2; ++ks)
#pragma unroll
      for (int m = 0; m < 4; ++m) {
        const int pr = m * 16 + l15;
        xf[m][ks] = *(const bf16x8*)(&As[cb][pr][(((ks * 4 + g4) ^ (pr & 7)) * 8)]);
      }
    mfmaS(xf, wfA);
    __syncthreads();
  }

  // ---- epilogue: D[co][pix]; l15 -> consecutive x: coalesced ----
#pragma unroll
  for (int n = 0; n < 2; ++n) {
    const int co = wid * 32 + n * 16 + g4 * 4;
#pragma unroll
    for (int m = 0; m < 4; ++m) {
      const int pl = m * 16 + l15;
      float* o = out + (size_t)(b * C_OUT + co) * 4096 + y0 * 64 + pl;
#pragma unroll
      for (int i = 0; i < 4; ++i)
        o[(size_t)i * 4096] = acc[n][m][i] + base_b[co + i];
    }
  }
}

extern "C" void kernel_launch(void* const* d_in, const int* in_sizes, int n_in,
                              void* d_out, int out_size, void* d_ws, size_t ws_size,
                              hipStream_t stream) {
  const float* x    = (const float*)d_in[0];
  const float* grid = (const float*)d_in[1];
  const float* sw   = (const float*)d_in[2];
  const float* bw   = (const float*)d_in[3];
  const float* bb   = (const float*)d_in[4];
  float* out = (float*)d_out;

  __bf16* wt3 = (__bf16*)d_ws;
  __bf16* xe  = (__bf16*)((char*)d_ws + XE_OFF);
  __bf16* se  = (__bf16*)((char*)d_ws + SE_OFF);

  prep_wt<<<NSTEPS, 256, 0, stream>>>(sw, bw, wt3);
  expand<<<(NEXP + 255) / 256, 256, 0, stream>>>(x, grid, xe, se);
  kan_gemm<<<512, 256, 0, stream>>>(xe, se, wt3, bb, out);
}